// Round 1
// baseline (1223.568 us; speedup 1.0000x reference)
//
#include <hip/hip_runtime.h>
#include <math.h>

#define BB 64
#define TT 2048
#define FF 128
#define HH 32
#define GG 128  // 4*H

__device__ __forceinline__ float sigmoidf_(float x) {
    return 1.0f / (1.0f + __expf(-x));
}
__device__ __forceinline__ float tanhf_(float x) {
    float xc = fminf(fmaxf(x, -15.f), 15.f);
    float e = __expf(-2.f * xc);
    return (1.f - e) / (1.f + e);
}

// ---------------- Kernel 1: xg[b,t,:] = X[b,t,:] @ Wx + bias ----------------
// Tile: 64 rows (b*T flattened) x 128 cols, K chunked by 32. 256 threads.
__global__ __launch_bounds__(256) void xg_gemm(const float* __restrict__ X,
                                               const float* __restrict__ Wx,
                                               const float* __restrict__ bias,
                                               float* __restrict__ xg) {
    __shared__ float XL[64 * 32];    // [row][fi]  8 KB
    __shared__ float WL[32 * 128];   // [fi][col] 16 KB
    const int tid = threadIdx.x;
    const int row0 = blockIdx.x * 64;
    const int j0 = (tid & 15) * 8;   // 8 output cols
    const int r0 = (tid >> 4) * 4;   // 4 output rows

    float acc[4][8];
#pragma unroll
    for (int r = 0; r < 4; ++r)
#pragma unroll
        for (int jj = 0; jj < 8; ++jj) acc[r][jj] = 0.f;

    for (int f0 = 0; f0 < FF; f0 += 32) {
        __syncthreads();  // protect LDS from previous chunk's readers
        // stage Wx chunk: rows f0..f0+31 x 128 cols = 4096 floats, contiguous
        {
            const float4* src = (const float4*)(Wx + f0 * GG);
            float4* dst = (float4*)WL;
            dst[tid]       = src[tid];
            dst[tid + 256] = src[tid + 256];
            dst[tid + 512] = src[tid + 512];
            dst[tid + 768] = src[tid + 768];
        }
        // stage X chunk: 64 rows x 32 floats (wave-contiguous LDS stores)
        {
            int lin = tid * 4;
            int row = lin >> 5;
            int fi  = lin & 31;
            ((float4*)XL)[tid] =
                *(const float4*)(X + (size_t)(row0 + row) * FF + f0 + fi);
            lin = (tid + 256) * 4;
            row = lin >> 5;
            fi  = lin & 31;
            ((float4*)XL)[tid + 256] =
                *(const float4*)(X + (size_t)(row0 + row) * FF + f0 + fi);
        }
        __syncthreads();
#pragma unroll 4
        for (int fi = 0; fi < 32; ++fi) {
            float xv[4];
#pragma unroll
            for (int r = 0; r < 4; ++r) xv[r] = XL[(r0 + r) * 32 + fi];
            float4 w0 = *(float4*)&WL[fi * GG + j0];
            float4 w1 = *(float4*)&WL[fi * GG + j0 + 4];
            float w[8] = {w0.x, w0.y, w0.z, w0.w, w1.x, w1.y, w1.z, w1.w};
#pragma unroll
            for (int r = 0; r < 4; ++r)
#pragma unroll
                for (int jj = 0; jj < 8; ++jj)
                    acc[r][jj] = fmaf(xv[r], w[jj], acc[r][jj]);
        }
    }
    // epilogue: add bias, store
    float bl[8];
#pragma unroll
    for (int jj = 0; jj < 8; ++jj) bl[jj] = bias[j0 + jj];
#pragma unroll
    for (int r = 0; r < 4; ++r) {
        float4 o0, o1;
        o0.x = acc[r][0] + bl[0]; o0.y = acc[r][1] + bl[1];
        o0.z = acc[r][2] + bl[2]; o0.w = acc[r][3] + bl[3];
        o1.x = acc[r][4] + bl[4]; o1.y = acc[r][5] + bl[5];
        o1.z = acc[r][6] + bl[6]; o1.w = acc[r][7] + bl[7];
        float* dst = xg + (size_t)(row0 + r0 + r) * GG + j0;
        *(float4*)dst = o0;
        *(float4*)(dst + 4) = o1;
    }
}

// ---------------- Kernel 2: sequential LSTM scan, one block per batch ------
// 128 threads: thread j owns gate column j. h broadcast via double-buffered LDS.
__global__ __launch_bounds__(128) void lstm_rec(const float* __restrict__ xg,
                                                const float* __restrict__ Wh,
                                                const float* __restrict__ Wd,
                                                const float* __restrict__ bd,
                                                float* __restrict__ out) {
    const int b = blockIdx.x;
    const int j = threadIdx.x;  // 0..127

    __shared__ float h_sh[2][HH];
    __shared__ float act_sh[GG];

    // Wh column j -> registers
    float wh[HH];
#pragma unroll
    for (int k = 0; k < HH; ++k) wh[k] = Wh[k * GG + j];

    if (j < HH) h_sh[0][j] = 0.f;
    float c = 0.f;

    const float* xgb = xg + (size_t)b * TT * GG + j;
    float x0 = xgb[0];
    float x1 = xgb[GG];
    __syncthreads();

    int cur = 0;
    for (int t = 0; t < TT; ++t) {
        float a = x0;
        x0 = x1;
        if (t + 2 < TT) x1 = xgb[(size_t)(t + 2) * GG];  // depth-2 prefetch

#pragma unroll
        for (int k = 0; k < HH; ++k) a = fmaf(h_sh[cur][k], wh[k], a);

        float act;
        if (j >= 2 * HH && j < 3 * HH) act = tanhf_(a);   // g gate
        else                           act = sigmoidf_(a); // i, f, o gates
        act_sh[j] = act;
        __syncthreads();

        if (j < HH) {
            float ig = act_sh[j];
            float fg = act_sh[HH + j];
            float gg = act_sh[2 * HH + j];
            float og = act_sh[3 * HH + j];
            c = fmaf(fg, c, ig * gg);
            h_sh[cur ^ 1][j] = og * tanhf_(c);
        }
        __syncthreads();
        cur ^= 1;
    }

    // out[b] = h_T @ Wd + bd
    if (j == 0) {
        float s = bd[0];
#pragma unroll
        for (int k = 0; k < HH; ++k) s = fmaf(h_sh[cur][k], Wd[k], s);
        out[b] = s;
    }
}

extern "C" void kernel_launch(void* const* d_in, const int* in_sizes, int n_in,
                              void* d_out, int out_size, void* d_ws, size_t ws_size,
                              hipStream_t stream) {
    const float* X    = (const float*)d_in[0];
    const float* Wx   = (const float*)d_in[1];
    const float* Wh   = (const float*)d_in[2];
    const float* bias = (const float*)d_in[3];
    const float* Wd   = (const float*)d_in[4];
    const float* bd   = (const float*)d_in[5];
    float* out = (float*)d_out;
    float* xg  = (float*)d_ws;  // 64*2048*128 floats = 64 MB

    hipLaunchKernelGGL(xg_gemm, dim3((BB * TT) / 64), dim3(256), 0, stream,
                       X, Wx, bias, xg);
    hipLaunchKernelGGL(lstm_rec, dim3(BB), dim3(128), 0, stream,
                       xg, Wh, Wd, bd, out);
}

// Round 2
// 796.662 us; speedup vs baseline: 1.5359x; 1.5359x over previous
//
#include <hip/hip_runtime.h>
#include <math.h>

#define BB 64
#define TT 2048
#define FF 128
#define HH 32
#define GG 128  // 4*H

// ---------------- Kernel 1: xg[b,t,:] = X[b,t,:] @ Wx + bias ----------------
// Tile: 64 rows (b*T flattened) x 128 cols, K chunked by 32. 256 threads.
__global__ __launch_bounds__(256) void xg_gemm(const float* __restrict__ X,
                                               const float* __restrict__ Wx,
                                               const float* __restrict__ bias,
                                               float* __restrict__ xg) {
    __shared__ float XL[64 * 32];    // [row][fi]  8 KB
    __shared__ float WL[32 * 128];   // [fi][col] 16 KB
    const int tid = threadIdx.x;
    const int row0 = blockIdx.x * 64;
    const int j0 = (tid & 15) * 8;   // 8 output cols
    const int r0 = (tid >> 4) * 4;   // 4 output rows

    float acc[4][8];
#pragma unroll
    for (int r = 0; r < 4; ++r)
#pragma unroll
        for (int jj = 0; jj < 8; ++jj) acc[r][jj] = 0.f;

    for (int f0 = 0; f0 < FF; f0 += 32) {
        __syncthreads();
        {
            const float4* src = (const float4*)(Wx + f0 * GG);
            float4* dst = (float4*)WL;
            dst[tid]       = src[tid];
            dst[tid + 256] = src[tid + 256];
            dst[tid + 512] = src[tid + 512];
            dst[tid + 768] = src[tid + 768];
        }
        {
            int lin = tid * 4;
            int row = lin >> 5;
            int fi  = lin & 31;
            ((float4*)XL)[tid] =
                *(const float4*)(X + (size_t)(row0 + row) * FF + f0 + fi);
            lin = (tid + 256) * 4;
            row = lin >> 5;
            fi  = lin & 31;
            ((float4*)XL)[tid + 256] =
                *(const float4*)(X + (size_t)(row0 + row) * FF + f0 + fi);
        }
        __syncthreads();
#pragma unroll 4
        for (int fi = 0; fi < 32; ++fi) {
            float xv[4];
#pragma unroll
            for (int r = 0; r < 4; ++r) xv[r] = XL[(r0 + r) * 32 + fi];
            float4 w0 = *(float4*)&WL[fi * GG + j0];
            float4 w1 = *(float4*)&WL[fi * GG + j0 + 4];
            float w[8] = {w0.x, w0.y, w0.z, w0.w, w1.x, w1.y, w1.z, w1.w};
#pragma unroll
            for (int r = 0; r < 4; ++r)
#pragma unroll
                for (int jj = 0; jj < 8; ++jj)
                    acc[r][jj] = fmaf(xv[r], w[jj], acc[r][jj]);
        }
    }
    float bl[8];
#pragma unroll
    for (int jj = 0; jj < 8; ++jj) bl[jj] = bias[j0 + jj];
#pragma unroll
    for (int r = 0; r < 4; ++r) {
        float4 o0, o1;
        o0.x = acc[r][0] + bl[0]; o0.y = acc[r][1] + bl[1];
        o0.z = acc[r][2] + bl[2]; o0.w = acc[r][3] + bl[3];
        o1.x = acc[r][4] + bl[4]; o1.y = acc[r][5] + bl[5];
        o1.z = acc[r][6] + bl[6]; o1.w = acc[r][7] + bl[7];
        float* dst = xg + (size_t)(row0 + r0 + r) * GG + j0;
        *(float4*)dst = o0;
        *(float4*)(dst + 4) = o1;
    }
}

// -------- helper: xor-32 swap of two values across the wave's halves --------
// (p,q) = swap(act0,act1): p={a0.lo,a1.lo}, q={a0.hi,a1.hi}
// (r,s) = swap(q,p):       r={a0.hi,a0.lo}=x32(a0), s={a1.hi,a1.lo}=x32(a1)
__device__ __forceinline__ void xor32_pair(float& a, float& b) {
#if __has_builtin(__builtin_amdgcn_permlane32_swap)
    auto pq = __builtin_amdgcn_permlane32_swap(__float_as_uint(a),
                                               __float_as_uint(b), false, false);
    auto rs = __builtin_amdgcn_permlane32_swap(pq[1], pq[0], false, false);
    a = __uint_as_float(rs[0]);
    b = __uint_as_float(rs[1]);
#else
    a = __shfl_xor(a, 32, 64);
    b = __shfl_xor(b, 32, 64);
#endif
}

__device__ __forceinline__ float rcp_(float x) {
    return __builtin_amdgcn_rcpf(x);
}

// ---------------- Kernel 2: single-wave barrier-free LSTM scan -------------
// 64 lanes per block (one block per batch element). Lane l owns gate columns
// l and l+64; lane l holds h[l&31] and c[l&31] (both halves redundant).
__global__ __launch_bounds__(64) void lstm_rec(const float* __restrict__ xg,
                                               const float* __restrict__ Wh,
                                               const float* __restrict__ Wd,
                                               const float* __restrict__ bd,
                                               float* __restrict__ out) {
    const int b = blockIdx.x;
    const int l = threadIdx.x;  // 0..63

    // Wh columns l and l+64 -> registers (64 VGPRs)
    float2 wh[HH];
#pragma unroll
    for (int k = 0; k < HH; ++k)
        wh[k] = make_float2(Wh[k * GG + l], Wh[k * GG + l + 64]);

    float h = 0.f;  // lane l: h[l & 31]
    float c = 0.f;  // lane l: c[l & 31]

    const float* xgb = xg + (size_t)b * TT * GG;

    // depth-3 prefetch of xg rows
    float2 x0 = make_float2(xgb[l],          xgb[l + 64]);
    float2 x1 = make_float2(xgb[GG + l],     xgb[GG + l + 64]);
    float2 x2 = make_float2(xgb[2 * GG + l], xgb[2 * GG + l + 64]);

#pragma unroll 4
    for (int t = 0; t < TT; ++t) {
        float2 a = x0;
        x0 = x1;
        x1 = x2;
        if (t + 3 < TT) {
            const float* p = xgb + (size_t)(t + 3) * GG;
            x2 = make_float2(p[l], p[l + 64]);
        }

        // a.x = gate col l (i|f), a.y = gate col l+64 (g|o)
#pragma unroll
        for (int k = 0; k < HH; ++k) {
            float hk = __uint_as_float(
                __builtin_amdgcn_readlane(__float_as_uint(h), k));
            a.x = fmaf(hk, wh[k].x, a.x);
            a.y = fmaf(hk, wh[k].y, a.y);
        }

        const bool lo_half = (l < HH);
        // act0: sigmoid for all lanes (i for lo, f for hi)
        float act0 = rcp_(1.f + __expf(-a.x));
        // act1: tanh(g) for lo half, sigmoid(o) for hi half.
        // tanh(x) = 2*sigmoid(2x) - 1  (branch-free via selects)
        float pre = lo_half ? 2.f * a.y : a.y;
        float s1 = rcp_(1.f + __expf(-pre));
        float act1 = lo_half ? fmaf(2.f, s1, -1.f) : s1;

        float act0x = act0, act1x = act1;
        xor32_pair(act0x, act1x);  // values from the opposite 32-lane half

        float ig = lo_half ? act0 : act0x;   // sigmoid(i)
        float fg = lo_half ? act0x : act0;   // sigmoid(f)
        float gg = lo_half ? act1 : act1x;   // tanh(g)
        float og = lo_half ? act1x : act1;   // sigmoid(o)

        c = fmaf(fg, c, ig * gg);
        // tanh(c) = 2/(1+exp(-2c)) - 1
        float tc = fmaf(2.f, rcp_(1.f + __expf(-2.f * c)), -1.f);
        h = og * tc;
    }

    // out[b] = h_T @ Wd + bd   (each h[k] appears twice across 64 lanes)
    float contrib = h * Wd[l & (HH - 1)];
#pragma unroll
    for (int off = 32; off >= 1; off >>= 1)
        contrib += __shfl_xor(contrib, off, 64);
    if (l == 0) out[b] = fmaf(0.5f, contrib, bd[0]);
}

extern "C" void kernel_launch(void* const* d_in, const int* in_sizes, int n_in,
                              void* d_out, int out_size, void* d_ws, size_t ws_size,
                              hipStream_t stream) {
    const float* X    = (const float*)d_in[0];
    const float* Wx   = (const float*)d_in[1];
    const float* Wh   = (const float*)d_in[2];
    const float* bias = (const float*)d_in[3];
    const float* Wd   = (const float*)d_in[4];
    const float* bd   = (const float*)d_in[5];
    float* out = (float*)d_out;
    float* xg  = (float*)d_ws;  // 64*2048*128 floats = 64 MB

    hipLaunchKernelGGL(xg_gemm, dim3((BB * TT) / 64), dim3(256), 0, stream,
                       X, Wx, bias, xg);
    hipLaunchKernelGGL(lstm_rec, dim3(BB), dim3(64), 0, stream,
                       xg, Wh, Wd, bd, out);
}

// Round 3
// 523.055 us; speedup vs baseline: 2.3393x; 1.5231x over previous
//
#include <hip/hip_runtime.h>
#include <math.h>

#define BB 64
#define TT 2048
#define FF 128
#define HH 32
#define GG 128  // 4*H

// gate-column prescale: sigma(a) = rcp(1 + exp2(S1*a)), tanh(a) = 2*rcp(1+exp2(S2*a))-1
#define S1f (-1.4426950408889634f)  // -log2(e)
#define S2f (-2.8853900817779268f)  // -2*log2(e)

// ---------------- Kernel 1: xg'[b][col][t] = scale[col]*(X[b,t,:]@Wx + b)[col]
// Tile: 64 rows (t within one b) x 128 cols, K chunked by 32. 256 threads.
__global__ __launch_bounds__(256) void xg_gemm(const float* __restrict__ X,
                                               const float* __restrict__ Wx,
                                               const float* __restrict__ bias,
                                               float* __restrict__ xgT) {
    __shared__ float XL[64 * 32];    // [row][fi]  8 KB
    __shared__ float WL[32 * 128];   // [fi][col] 16 KB
    const int tid = threadIdx.x;
    const int row0 = blockIdx.x * 64;   // flattened b*T + t0 (one b per block)
    const int j0 = (tid & 15) * 8;   // 8 output cols
    const int r0 = (tid >> 4) * 4;   // 4 output rows (consecutive t)

    float acc[4][8];
#pragma unroll
    for (int r = 0; r < 4; ++r)
#pragma unroll
        for (int jj = 0; jj < 8; ++jj) acc[r][jj] = 0.f;

    for (int f0 = 0; f0 < FF; f0 += 32) {
        __syncthreads();
        {
            const float4* src = (const float4*)(Wx + f0 * GG);
            float4* dst = (float4*)WL;
            dst[tid]       = src[tid];
            dst[tid + 256] = src[tid + 256];
            dst[tid + 512] = src[tid + 512];
            dst[tid + 768] = src[tid + 768];
        }
        {
            int lin = tid * 4;
            int row = lin >> 5;
            int fi  = lin & 31;
            ((float4*)XL)[tid] =
                *(const float4*)(X + (size_t)(row0 + row) * FF + f0 + fi);
            lin = (tid + 256) * 4;
            row = lin >> 5;
            fi  = lin & 31;
            ((float4*)XL)[tid + 256] =
                *(const float4*)(X + (size_t)(row0 + row) * FF + f0 + fi);
        }
        __syncthreads();
#pragma unroll 4
        for (int fi = 0; fi < 32; ++fi) {
            float xv[4];
#pragma unroll
            for (int r = 0; r < 4; ++r) xv[r] = XL[(r0 + r) * 32 + fi];
            float4 w0 = *(float4*)&WL[fi * GG + j0];
            float4 w1 = *(float4*)&WL[fi * GG + j0 + 4];
            float w[8] = {w0.x, w0.y, w0.z, w0.w, w1.x, w1.y, w1.z, w1.w};
#pragma unroll
            for (int r = 0; r < 4; ++r)
#pragma unroll
                for (int jj = 0; jj < 8; ++jj)
                    acc[r][jj] = fmaf(xv[r], w[jj], acc[r][jj]);
        }
    }
    // epilogue: add bias, prescale, store TRANSPOSED ([b][col][t], float4 on t)
    const int b  = row0 >> 11;            // row0 / 2048
    const int t0 = (row0 & 2047) + r0;
    float bl[8];
#pragma unroll
    for (int jj = 0; jj < 8; ++jj) bl[jj] = bias[j0 + jj];
#pragma unroll
    for (int jj = 0; jj < 8; ++jj) {
        const int j = j0 + jj;
        const float sc = (j >= 64 && j < 96) ? S2f : S1f;
        float4 o;
        o.x = (acc[0][jj] + bl[jj]) * sc;
        o.y = (acc[1][jj] + bl[jj]) * sc;
        o.z = (acc[2][jj] + bl[jj]) * sc;
        o.w = (acc[3][jj] + bl[jj]) * sc;
        *(float4*)(xgT + ((size_t)b * GG + j) * TT + t0) = o;
    }
}

__device__ __forceinline__ float rcp_(float x) { return __builtin_amdgcn_rcpf(x); }
__device__ __forceinline__ float exp2_(float x) { return __builtin_amdgcn_exp2f(x); }

// ---------------- Kernel 2: single-wave barrier-free LSTM scan -------------
// 64 lanes per block (one block per batch element). Lane l owns gate columns
// l and l+64; lane l holds h[l&31], c[l&31] (both halves redundant).
__global__ __launch_bounds__(64) void lstm_rec(const float* __restrict__ xgT,
                                               const float* __restrict__ Wh,
                                               const float* __restrict__ Wd,
                                               const float* __restrict__ bd,
                                               float* __restrict__ out) {
    const int b = blockIdx.x;
    const int l = threadIdx.x;  // 0..63
    const bool lo = (l < HH);

    // Wh columns l and l+64 -> registers, prescaled per gate group
    const float scx = S1f;                 // col l: i (lo) or f (hi)
    const float scy = lo ? S2f : S1f;      // col l+64: g (lo) or o (hi)
    float2 wh[HH];
#pragma unroll
    for (int k = 0; k < HH; ++k)
        wh[k] = make_float2(Wh[k * GG + l] * scx, Wh[k * GG + l + 64] * scy);

    // per-lane affine for act1: tanh = 2*s-1 (lo), sigmoid = s (hi)
    const float A1 = lo ? 2.f : 1.f;
    const float B1 = lo ? -1.f : 0.f;

    float h = 0.f;  // lane l: h[l & 31]
    float c = 0.f;  // lane l: c[l & 31]

    const float* pX = xgT + ((size_t)b * GG + l) * TT;        // col l, along t
    const float* pY = xgT + ((size_t)b * GG + l + 64) * TT;   // col l+64

    float4 curX = *(const float4*)(pX);
    float4 curY = *(const float4*)(pY);
    float4 nxtX = *(const float4*)(pX + 4);
    float4 nxtY = *(const float4*)(pY + 4);

    auto step = [&](float xi, float xy) __attribute__((always_inline)) {
        // gate matvec: 4-way split accumulator chains, h broadcast via readlane
        float ax[4] = {xi, 0.f, 0.f, 0.f};
        float ay[4] = {xy, 0.f, 0.f, 0.f};
#pragma unroll
        for (int kc = 0; kc < 4; ++kc) {
#pragma unroll
            for (int k = 0; k < 8; ++k) {
                const int kk = kc * 8 + k;
                float hk = __uint_as_float(
                    __builtin_amdgcn_readlane(__float_as_uint(h), kk));
                ax[kc] = fmaf(hk, wh[kk].x, ax[kc]);
                ay[kc] = fmaf(hk, wh[kk].y, ay[kc]);
            }
        }
        float a0 = (ax[0] + ax[1]) + (ax[2] + ax[3]);  // prescaled preact, col l
        float a1 = (ay[0] + ay[1]) + (ay[2] + ay[3]);  // prescaled preact, col l+64

        // act0 = sigmoid (i|f); act1 = tanh (g) on lo, sigmoid (o) on hi
        float act0 = rcp_(1.f + exp2_(a0));
        float act1 = fmaf(A1, rcp_(1.f + exp2_(a1)), B1);

        // two independent half-swaps:
        // p={i|g} q={f|o} u={g|i} v={o|f}
        auto pq = __builtin_amdgcn_permlane32_swap(__float_as_uint(act0),
                                                   __float_as_uint(act1), false, false);
        auto uv = __builtin_amdgcn_permlane32_swap(__float_as_uint(act1),
                                                   __float_as_uint(act0), false, false);
        float p = __uint_as_float(pq[0]);
        float q = __uint_as_float(pq[1]);
        float u = __uint_as_float(uv[0]);
        float v = __uint_as_float(uv[1]);

        float f_all = lo ? q : act0;   // sigmoid(f)
        float o_all = lo ? v : act1;   // sigmoid(o)
        c = fmaf(f_all, c, u * p);     // u*p = i*g in every lane
        float tc = fmaf(2.f, rcp_(1.f + exp2_(c * S2f)), -1.f);  // tanh(c)
        h = o_all * tc;
    };

#pragma unroll 1
    for (int t4 = 0; t4 < TT; t4 += 4) {
        float4 uX = curX, uY = curY;
        curX = nxtX; curY = nxtY;
        if (t4 + 8 < TT) {
            nxtX = *(const float4*)(pX + t4 + 8);
            nxtY = *(const float4*)(pY + t4 + 8);
        }
        step(uX.x, uY.x);
        step(uX.y, uY.y);
        step(uX.z, uY.z);
        step(uX.w, uY.w);
    }

    // out[b] = h_T @ Wd + bd   (each h[k] appears twice across 64 lanes)
    float contrib = h * Wd[l & (HH - 1)];
#pragma unroll
    for (int off = 32; off >= 1; off >>= 1)
        contrib += __shfl_xor(contrib, off, 64);
    if (l == 0) out[b] = fmaf(0.5f, contrib, bd[0]);
}

extern "C" void kernel_launch(void* const* d_in, const int* in_sizes, int n_in,
                              void* d_out, int out_size, void* d_ws, size_t ws_size,
                              hipStream_t stream) {
    const float* X    = (const float*)d_in[0];
    const float* Wx   = (const float*)d_in[1];
    const float* Wh   = (const float*)d_in[2];
    const float* bias = (const float*)d_in[3];
    const float* Wd   = (const float*)d_in[4];
    const float* bd   = (const float*)d_in[5];
    float* out = (float*)d_out;
    float* xgT = (float*)d_ws;  // [64][128][2048] floats = 64 MB

    hipLaunchKernelGGL(xg_gemm, dim3((BB * TT) / 64), dim3(256), 0, stream,
                       X, Wx, bias, xgT);
    hipLaunchKernelGGL(lstm_rec, dim3(BB), dim3(64), 0, stream,
                       xgT, Wh, Wd, bd, out);
}